// Round 4
// baseline (2433.055 us; speedup 1.0000x reference)
//
#include <hip/hip_runtime.h>

typedef float float2v __attribute__((ext_vector_type(2)));
typedef float float4v __attribute__((ext_vector_type(4)));

constexpr int B_ = 64, G_ = 8, N_ = 88, T_ = 64, D_ = 88, O_ = 64;
constexpr int NT = N_ * T_;          // 5632 (k dimension per g)
constexpr int M_ = D_ * O_;          // 5632 outputs per b
constexpr int KQ = NT / 4;           // 1408 float4 groups per b
constexpr int KCH = 64;              // k per chunk (== T_, so mask row aligns)
constexpr int NCH = NT / KCH;        // 88 chunks
constexpr int DPW = 22;              // d's per wave (88 = 4*22)
constexpr int KSPLIT = 2;            // k-split (atomic partials per output = KSPLIT*G = 16)
constexpr int CPJ = NCH / KSPLIT;    // 44 chunks per job
constexpr int NJOBS = KSPLIT * (D_ / DPW) * O_ * G_;  // 4096 wave-jobs
constexpr size_t XT4_ELEMS = (size_t)KQ * B_;          // 90112 float4s
constexpr size_t MASKF_OFF = XT4_ELEMS * 16;           // byte offset of maskf in ws

// ---- prep: transpose x into xT4[kq][b] (float4 of 4 consecutive k), mask -> float ----
__global__ void mlm_prep(const float* __restrict__ x, const int* __restrict__ mask,
                         float4v* __restrict__ xT4, float* __restrict__ maskf) {
  int id = blockIdx.x * 256 + threadIdx.x;
  if (id < (int)XT4_ELEMS) {
    int b = id / KQ, kq = id % KQ;               // coalesced read along k
    float4v v = *(const float4v*)(x + (size_t)b * NT + 4 * (size_t)kq);
    xT4[(size_t)kq * B_ + b] = v;
  } else {
    int j = id - (int)XT4_ELEMS;
    if (j < O_ * T_) maskf[j] = (float)mask[j];
  }
}

// ---- init: out[b][m] = bias[m] ----
__global__ void mlm_init(const float4v* __restrict__ bias4, float4v* __restrict__ out4) {
  int id = blockIdx.x * 256 + threadIdx.x;       // 90112 = B_*M_/4
  int m4 = id % (M_ / 4);
  out4[id] = bias4[m4];
}

// ---- main: wave-job = (g, o, d-block of 22, k-half); lane = b ----
// Weights are wave-uniform (job readfirstlane'd): scalar s_load path if the
// compiler scalarizes, uniform-address vector loads otherwise (one cache
// line per instr either way). Inner loop software-pipelines one d-row of
// weight quads ahead of the FMA chain so >=8 quads/wave are in flight.
__global__ __launch_bounds__(256, 2) void mlm_main(
    const float* __restrict__ w, const float* __restrict__ y,
    const float4v* __restrict__ xT4, const float* __restrict__ maskf,
    float* __restrict__ out) {
  const int lane = threadIdx.x & 63;
  int job = (int)(blockIdx.x * 4) + (threadIdx.x >> 6);
  job = __builtin_amdgcn_readfirstlane(job);     // wave-uniform
  const int ks   = job & (KSPLIT - 1);
  const int dblk = (job >> 1) & 3;
  const int o    = (job >> 3) & 63;
  const int g    = (job >> 9) & 7;

  const int b = lane;
  const float yv = y[b * G_ + g];
  const size_t drow = (size_t)O_ * NT;           // element stride between d's
  const float* wbase = w + (size_t)((g * D_ + dblk * DPW) * O_ + o) * NT;
  const float2v* __restrict__ mrow = (const float2v*)(maskf + o * T_);  // uniform

  float2v acc[DPW];
#pragma unroll
  for (int i = 0; i < DPW; ++i) acc[i] = float2v{0.f, 0.f};

  for (int c = ks * CPJ; c < (ks + 1) * CPJ; ++c) {
    const int k0 = c * KCH;                      // k0 % 64 == 0 -> t = k&63 aligns with mask row
    // two half-chunks of 32 k each: xs[16] keeps VGPR pressure low
#pragma unroll
    for (int h = 0; h < 2; ++h) {
      const int kh = k0 + 32 * h;
      float2v xs[16];
      const float4v* xp = xT4 + (size_t)(kh >> 2) * B_ + b;
#pragma unroll
      for (int i = 0; i < 8; ++i) {
        float4v r = xp[(size_t)i * B_];          // coalesced, L2-resident
        float2v ma = mrow[16 * h + 2 * i];
        float2v mb = mrow[16 * h + 2 * i + 1];
        xs[2 * i]     = float2v{r.x, r.y} * ma * yv;
        xs[2 * i + 1] = float2v{r.z, r.w} * mb * yv;
      }
      // 22 weight rows (128 B each, 8 explicit dwordx4 loads per row),
      // software-pipelined one row ahead: loads of row dd+1 issue before
      // the FMA chain of row dd.
      float4v cur[8], nxt[8];
      const float4v* wp0 = (const float4v*)(wbase + kh);
#pragma unroll
      for (int p = 0; p < 8; ++p) cur[p] = wp0[p];
#pragma unroll
      for (int dd = 0; dd < DPW; ++dd) {
        const float4v* wpn = (const float4v*)(wbase + (size_t)(dd + 1) * drow + kh);
#pragma unroll
        for (int p = 0; p < 8; ++p)
          nxt[p] = (dd + 1 < DPW) ? wpn[p] : float4v{0.f, 0.f, 0.f, 0.f};
        float2v t0{0.f, 0.f}, t1{0.f, 0.f};      // 2 chains to hide fma latency
#pragma unroll
        for (int p = 0; p < 8; ++p) {
          t0 = __builtin_elementwise_fma(float2v{cur[p].x, cur[p].y}, xs[2 * p],     t0);
          t1 = __builtin_elementwise_fma(float2v{cur[p].z, cur[p].w}, xs[2 * p + 1], t1);
        }
        acc[dd] += t0 + t1;
#pragma unroll
        for (int p = 0; p < 8; ++p) cur[p] = nxt[p];   // renamed away under unroll
      }
    }
  }
#pragma unroll
  for (int dd = 0; dd < DPW; ++dd) {
    float v = acc[dd].x + acc[dd].y;
    atomicAdd(out + (size_t)b * M_ + (size_t)(dblk * DPW + dd) * O_ + o, v);
  }
}

extern "C" void kernel_launch(void* const* d_in, const int* in_sizes, int n_in,
                              void* d_out, int out_size, void* d_ws, size_t ws_size,
                              hipStream_t stream) {
  const float* x    = (const float*)d_in[0];
  const float* y    = (const float*)d_in[1];
  const float* wgt  = (const float*)d_in[2];
  const float* bias = (const float*)d_in[3];
  const int*   mask = (const int*)d_in[4];
  float* out = (float*)d_out;

  float4v* xT4   = (float4v*)d_ws;
  float*   maskf = (float*)((char*)d_ws + MASKF_OFF);

  // 1) transpose x + mask->float   2) out = bias   3) main accumulate
  int prep_threads = (int)XT4_ELEMS + O_ * T_;                   // 94208
  hipLaunchKernelGGL(mlm_prep, dim3((prep_threads + 255) / 256), dim3(256), 0, stream,
                     x, mask, xT4, maskf);
  hipLaunchKernelGGL(mlm_init, dim3((B_ * M_ / 4) / 256), dim3(256), 0, stream,
                     (const float4v*)bias, (float4v*)out);
  hipLaunchKernelGGL(mlm_main, dim3(NJOBS / 4), dim3(256), 0, stream,
                     wgt, y, xT4, maskf, out);
}